// Round 2
// baseline (275.517 us; speedup 1.0000x reference)
//
#include <hip/hip_runtime.h>
#include <math.h>

#define K_KP 17
#define HM 56
#define HW (HM * HM)                 // 3136
#define N_ROWS 1024
#define NK_ROWS (N_ROWS * K_KP)      // 17408
#define KP_META_BLOCKS (NK_ROWS / 256)   // 68 (divides exactly)
#define GRID (KP_META_BLOCKS + 1)        // 69: blocks 0..67 keypoints, 68 cls/box
#define C_CLS 8
#define IGNORE_LABEL 7
#define BETA_C (1.0f / 9.0f)

// ws layout: per-block partial slots, 5 floats each, written UNCONDITIONALLY by
// every block (zeros if no contribution) -> no zero-init / memset node needed.
//   slot[0]=kp_nll_sum  slot[1]=kp_valid_cnt  slot[2]=cls_nll_sum
//   slot[3]=keep_cnt    slot[4]=box_sl1_sum

__global__ __launch_bounds__(256) void roiheads_main(
    const float* __restrict__ class_logits,      // (1024, 8)
    const float* __restrict__ box_regression,    // (1024, 32)
    const float* __restrict__ regression_targets,// (1024, 4)
    const float* __restrict__ proposals,         // (1024, 4)
    const float* __restrict__ gt_keypoints,      // (256, 17, 3)
    const float* __restrict__ keypoint_logits,   // (1024, 17, 56, 56)
    const int*   __restrict__ labels,            // (1024,)
    const int*   __restrict__ kmi,               // (1024,)
    float* __restrict__ ws)
{
    const int bid  = blockIdx.x;
    const int tid  = threadIdx.x;
    const int lane = tid & 63;
    const int wid  = tid >> 6;

    __shared__ int   q_r[256];
    __shared__ int   q_lin[256];
    __shared__ int   q_cnt;
    __shared__ float w0[4], w1[4], w2[4];

    float p0 = 0.0f, p1 = 0.0f, p2 = 0.0f, p3 = 0.0f, p4 = 0.0f;

    if (bid < KP_META_BLOCKS) {
        // ---- keypoint CE: 1 thread per row for metadata, worklist for softmax ----
        if (tid == 0) q_cnt = 0;
        __syncthreads();

        const int r = bid * 256 + tid;
        const int n = r / K_KP;
        const int k = r - n * K_KP;
        const int g = kmi[n];
        const float* kp = gt_keypoints + ((size_t)g * K_KP + k) * 3;
        const float kx  = kp[0];
        const float ky  = kp[1];
        const float vis = kp[2];
        const float4 pr = ((const float4*)proposals)[n];   // x1,y1,x2,y2
        const float sx = (float)HM / (pr.z - pr.x);
        const float sy = (float)HM / (pr.w - pr.y);
        int xi = (int)floorf((kx - pr.x) * sx);
        int yi = (int)floorf((ky - pr.y) * sy);
        if (kx == pr.z) xi = HM - 1;
        if (ky == pr.w) yi = HM - 1;
        const bool valid = (xi >= 0) & (yi >= 0) & (xi < HM) & (yi < HM) & (vis > 0.0f);
        if (valid) {
            const int p = atomicAdd(&q_cnt, 1);
            q_r[p]   = r;
            q_lin[p] = yi * HM + xi;
        }
        __syncthreads();
        const int cnt = q_cnt;

        // waves drain the worklist: one full wave per valid row
        float my_s = 0.0f, my_c = 0.0f;   // meaningful on lane 0 only
        for (int i = wid; i < cnt; i += 4) {
            const int rr = q_r[i];
            const float* row = keypoint_logits + (size_t)rr * HW;
            const float4* rp = (const float4*)row;
            float m = -INFINITY, s = 0.0f;
            #pragma unroll
            for (int it = 0; it < 13; ++it) {
                const int idx = it * 64 + lane;
                if (idx < HW / 4) {
                    const float4 v = rp[idx];
                    float vals[4] = {v.x, v.y, v.z, v.w};
                    #pragma unroll
                    for (int j = 0; j < 4; ++j) {
                        const float x = vals[j];
                        if (x > m) { s = s * expf(m - x) + 1.0f; m = x; }
                        else       { s += expf(x - m); }
                    }
                }
            }
            #pragma unroll
            for (int off = 32; off > 0; off >>= 1) {
                const float om = __shfl_down(m, off, 64);
                const float os = __shfl_down(s, off, 64);
                const float nm = fmaxf(m, om);
                s = s * expf(m - nm) + os * expf(om - nm);
                m = nm;
            }
            if (lane == 0) {
                const float xt = row[q_lin[i]];
                my_s += m + logf(s) - xt;
                my_c += 1.0f;
            }
        }
        if (lane == 0) { w0[wid] = my_s; w1[wid] = my_c; }
        __syncthreads();
        if (tid == 0) {
            p0 = w0[0] + w0[1] + w0[2] + w0[3];
            p1 = w1[0] + w1[1] + w1[2] + w1[3];
        }
    } else {
        // ---- classification CE + box smooth-L1: 256 threads x 4 proposals ----
        float cls_part = 0.0f, keep_part = 0.0f, box_part = 0.0f;
        #pragma unroll
        for (int j = 0; j < 4; ++j) {
            const int n = j * 256 + tid;
            const int label = labels[n];
            const float* cl = class_logits + (size_t)n * C_CLS;
            float m = cl[0];
            #pragma unroll
            for (int c = 1; c < C_CLS; ++c) m = fmaxf(m, cl[c]);
            float s = 0.0f;
            #pragma unroll
            for (int c = 0; c < C_CLS; ++c) s += expf(cl[c] - m);
            const float nll  = m + logf(s) - cl[label];
            const float keep = (label != IGNORE_LABEL) ? 1.0f : 0.0f;
            cls_part  += keep * nll;
            keep_part += keep;
            if (label > 0) {
                #pragma unroll
                for (int c = 0; c < 4; ++c) {
                    const float d = box_regression[(size_t)n * 32 + label * 4 + c]
                                  - regression_targets[(size_t)n * 4 + c];
                    const float ad = fabsf(d);
                    box_part += (ad < BETA_C) ? 0.5f * d * d / BETA_C : ad - 0.5f * BETA_C;
                }
            }
        }
        #pragma unroll
        for (int off = 32; off > 0; off >>= 1) {
            cls_part  += __shfl_down(cls_part,  off, 64);
            keep_part += __shfl_down(keep_part, off, 64);
            box_part  += __shfl_down(box_part,  off, 64);
        }
        if (lane == 0) { w0[wid] = cls_part; w1[wid] = keep_part; w2[wid] = box_part; }
        __syncthreads();
        if (tid == 0) {
            p2 = w0[0] + w0[1] + w0[2] + w0[3];
            p3 = w1[0] + w1[1] + w1[2] + w1[3];
            p4 = w2[0] + w2[1] + w2[2] + w2[3];
        }
    }

    // every block writes its full 5-float slot unconditionally (no init needed)
    if (tid == 0) {
        float* slot = ws + (size_t)bid * 5;
        slot[0] = p0; slot[1] = p1; slot[2] = p2; slot[3] = p3; slot[4] = p4;
    }
}

__global__ __launch_bounds__(128) void roiheads_finalize(
    const float* __restrict__ ws, float* __restrict__ out)
{
    __shared__ float acc[5];
    const int tid = threadIdx.x;
    if (tid < 5) acc[tid] = 0.0f;
    __syncthreads();
    float v[5] = {0.0f, 0.0f, 0.0f, 0.0f, 0.0f};
    if (tid < GRID) {
        const float* slot = ws + (size_t)tid * 5;
        #pragma unroll
        for (int j = 0; j < 5; ++j) v[j] = slot[j];
    }
    #pragma unroll
    for (int j = 0; j < 5; ++j) atomicAdd(&acc[j], v[j]);
    __syncthreads();
    if (tid == 0) {
        out[0] = acc[2] / fmaxf(acc[3], 1.0f);     // classification loss
        out[1] = acc[4] / (float)N_ROWS;           // box loss
        out[2] = acc[0] / fmaxf(acc[1], 1.0f);     // keypoint loss
    }
}

extern "C" void kernel_launch(void* const* d_in, const int* in_sizes, int n_in,
                              void* d_out, int out_size, void* d_ws, size_t ws_size,
                              hipStream_t stream) {
    const float* class_logits       = (const float*)d_in[0];
    const float* box_regression     = (const float*)d_in[1];
    const float* regression_targets = (const float*)d_in[2];
    const float* proposals          = (const float*)d_in[3];
    const float* gt_keypoints       = (const float*)d_in[4];
    const float* keypoint_logits    = (const float*)d_in[5];
    const int*   labels             = (const int*)d_in[6];
    const int*   kmi                = (const int*)d_in[7];
    float* ws  = (float*)d_ws;
    float* out = (float*)d_out;

    roiheads_main<<<GRID, 256, 0, stream>>>(
        class_logits, box_regression, regression_targets, proposals,
        gt_keypoints, keypoint_logits, labels, kmi, ws);

    roiheads_finalize<<<1, 128, 0, stream>>>(ws, out);
}

// Round 3
// 267.649 us; speedup vs baseline: 1.0294x; 1.0294x over previous
//
#include <hip/hip_runtime.h>
#include <math.h>

#define K_KP 17
#define HM 56
#define HW (HM * HM)                 // 3136
#define N_ROWS 1024
#define NK_ROWS (N_ROWS * K_KP)      // 17408
#define KP_META_BLOCKS (NK_ROWS / 256)   // 68 (divides exactly)
#define GRID (KP_META_BLOCKS + 1)        // 69: blocks 0..67 keypoints, 68 cls/box+final
#define C_CLS 8
#define IGNORE_LABEL 7
#define BETA_C (1.0f / 9.0f)
#define FLAG_MAGIC 0x13579BDFu       // != 0xAAAAAAAA poison

// ws layout:
//   floats [0 .. 2*KP_META_BLOCKS)       : per-keypoint-block {kp_nll_sum, kp_cnt}
//   uint32 at ws + 2*KP_META_BLOCKS ...  : per-keypoint-block done flag (MAGIC)
// Flags start as 0xAAAAAAAA (harness poison, guaranteed before every launch),
// so "flag == MAGIC" means "this iteration's partials are published".
// release/acquire at AGENT scope handles cross-XCD L2 non-coherence (G16).

__global__ __launch_bounds__(256) void roiheads_fused(
    const float* __restrict__ class_logits,      // (1024, 8)
    const float* __restrict__ box_regression,    // (1024, 32)
    const float* __restrict__ regression_targets,// (1024, 4)
    const float* __restrict__ proposals,         // (1024, 4)
    const float* __restrict__ gt_keypoints,      // (256, 17, 3)
    const float* __restrict__ keypoint_logits,   // (1024, 17, 56, 56)
    const int*   __restrict__ labels,            // (1024,)
    const int*   __restrict__ kmi,               // (1024,)
    float* __restrict__ ws,
    float* __restrict__ out)
{
    const int bid  = blockIdx.x;
    const int tid  = threadIdx.x;
    const int lane = tid & 63;
    const int wid  = tid >> 6;

    float* slots = ws;                                    // 2 floats / kp block
    unsigned int* flags = (unsigned int*)(ws + 2 * KP_META_BLOCKS);

    if (bid < KP_META_BLOCKS) {
        // ================= keypoint blocks =================
        __shared__ int   q_r[256];
        __shared__ int   q_lin[256];
        __shared__ int   q_cnt;
        __shared__ float w0[4], w1[4];
        if (tid == 0) q_cnt = 0;
        __syncthreads();

        // --- metadata: 1 thread per (n,k) row ---
        const int r = bid * 256 + tid;
        const int n = r / K_KP;
        const int k = r - n * K_KP;
        const int g = kmi[n];
        const float* kp = gt_keypoints + ((size_t)g * K_KP + k) * 3;
        const float kx  = kp[0];
        const float ky  = kp[1];
        const float vis = kp[2];
        const float4 pr = ((const float4*)proposals)[n];   // x1,y1,x2,y2
        const float sx = (float)HM / (pr.z - pr.x);
        const float sy = (float)HM / (pr.w - pr.y);
        int xi = (int)floorf((kx - pr.x) * sx);
        int yi = (int)floorf((ky - pr.y) * sy);
        if (kx == pr.z) xi = HM - 1;
        if (ky == pr.w) yi = HM - 1;
        const bool valid = (xi >= 0) & (yi >= 0) & (xi < HM) & (yi < HM) & (vis > 0.0f);
        if (valid) {
            const int p = atomicAdd(&q_cnt, 1);
            q_r[p]   = r;
            q_lin[p] = yi * HM + xi;
        }
        __syncthreads();
        const int cnt = q_cnt;

        // --- drain worklist: one wave per valid row, two-pass register softmax ---
        float my_s = 0.0f, my_c = 0.0f;   // meaningful on lane 0 only
        for (int i = wid; i < cnt; i += 4) {
            const int rr = q_r[i];
            const float* row = keypoint_logits + (size_t)rr * HW;
            const float4* rp = (const float4*)row;

            float xv[52];
            #pragma unroll
            for (int it = 0; it < 13; ++it) {
                const int idx = it * 64 + lane;
                float4 v;
                if (it < 12 || lane < (HW / 4 - 768)) {      // 784-768=16
                    v = rp[idx];
                } else {
                    v = make_float4(-INFINITY, -INFINITY, -INFINITY, -INFINITY);
                }
                xv[it * 4 + 0] = v.x; xv[it * 4 + 1] = v.y;
                xv[it * 4 + 2] = v.z; xv[it * 4 + 3] = v.w;
            }
            // pass 1: max (4-way ILP tree, then wave reduce)
            float m0 = -INFINITY, m1 = -INFINITY, m2 = -INFINITY, m3 = -INFINITY;
            #pragma unroll
            for (int j = 0; j < 13; ++j) {
                m0 = fmaxf(m0, xv[4 * j + 0]); m1 = fmaxf(m1, xv[4 * j + 1]);
                m2 = fmaxf(m2, xv[4 * j + 2]); m3 = fmaxf(m3, xv[4 * j + 3]);
            }
            float m = fmaxf(fmaxf(m0, m1), fmaxf(m2, m3));
            #pragma unroll
            for (int off = 32; off > 0; off >>= 1)
                m = fmaxf(m, __shfl_xor(m, off, 64));
            // pass 2: sum of exp (independent expf, 4 accumulators)
            float s0 = 0.0f, s1 = 0.0f, s2 = 0.0f, s3 = 0.0f;
            #pragma unroll
            for (int j = 0; j < 13; ++j) {
                s0 += expf(xv[4 * j + 0] - m); s1 += expf(xv[4 * j + 1] - m);
                s2 += expf(xv[4 * j + 2] - m); s3 += expf(xv[4 * j + 3] - m);
            }
            float s = (s0 + s1) + (s2 + s3);
            #pragma unroll
            for (int off = 32; off > 0; off >>= 1)
                s += __shfl_xor(s, off, 64);
            if (lane == 0) {
                const float xt = row[q_lin[i]];
                my_s += m + logf(s) - xt;
                my_c += 1.0f;
            }
        }
        if (lane == 0) { w0[wid] = my_s; w1[wid] = my_c; }
        __syncthreads();
        if (tid == 0) {
            slots[bid * 2 + 0] = w0[0] + w0[1] + w0[2] + w0[3];
            slots[bid * 2 + 1] = w1[0] + w1[1] + w1[2] + w1[3];
            __hip_atomic_store(&flags[bid], FLAG_MAGIC,
                               __ATOMIC_RELEASE, __HIP_MEMORY_SCOPE_AGENT);
        }
    } else {
        // ================= cls/box + finalize block =================
        __shared__ float red[5];   // 0:cls 1:keep 2:box 3:kp_nll 4:kp_cnt
        if (tid < 5) red[tid] = 0.0f;
        __syncthreads();

        float cls_part = 0.0f, keep_part = 0.0f, box_part = 0.0f;
        #pragma unroll
        for (int j = 0; j < 4; ++j) {
            const int n = j * 256 + tid;
            const int label = labels[n];
            const float* cl = class_logits + (size_t)n * C_CLS;
            float m = cl[0];
            #pragma unroll
            for (int c = 1; c < C_CLS; ++c) m = fmaxf(m, cl[c]);
            float s = 0.0f;
            #pragma unroll
            for (int c = 0; c < C_CLS; ++c) s += expf(cl[c] - m);
            const float nll  = m + logf(s) - cl[label];
            const float keep = (label != IGNORE_LABEL) ? 1.0f : 0.0f;
            cls_part  += keep * nll;
            keep_part += keep;
            if (label > 0) {
                #pragma unroll
                for (int c = 0; c < 4; ++c) {
                    const float d = box_regression[(size_t)n * 32 + label * 4 + c]
                                  - regression_targets[(size_t)n * 4 + c];
                    const float ad = fabsf(d);
                    box_part += (ad < BETA_C) ? 0.5f * d * d / BETA_C : ad - 0.5f * BETA_C;
                }
            }
        }
        #pragma unroll
        for (int off = 32; off > 0; off >>= 1) {
            cls_part  += __shfl_down(cls_part,  off, 64);
            keep_part += __shfl_down(keep_part, off, 64);
            box_part  += __shfl_down(box_part,  off, 64);
        }
        if (lane == 0) {
            atomicAdd(&red[0], cls_part);
            atomicAdd(&red[1], keep_part);
            atomicAdd(&red[2], box_part);
        }

        // wait for keypoint blocks (acquire pairs with their release)
        if (tid < KP_META_BLOCKS) {
            while (__hip_atomic_load(&flags[tid], __ATOMIC_ACQUIRE,
                                     __HIP_MEMORY_SCOPE_AGENT) != FLAG_MAGIC) {
                __builtin_amdgcn_s_sleep(1);
            }
            const float s0 = slots[tid * 2 + 0];
            const float s1 = slots[tid * 2 + 1];
            atomicAdd(&red[3], s0);
            atomicAdd(&red[4], s1);
        }
        __syncthreads();
        if (tid == 0) {
            out[0] = red[0] / fmaxf(red[1], 1.0f);   // classification loss
            out[1] = red[2] / (float)N_ROWS;         // box loss
            out[2] = red[3] / fmaxf(red[4], 1.0f);   // keypoint loss
        }
    }
}

extern "C" void kernel_launch(void* const* d_in, const int* in_sizes, int n_in,
                              void* d_out, int out_size, void* d_ws, size_t ws_size,
                              hipStream_t stream) {
    const float* class_logits       = (const float*)d_in[0];
    const float* box_regression     = (const float*)d_in[1];
    const float* regression_targets = (const float*)d_in[2];
    const float* proposals          = (const float*)d_in[3];
    const float* gt_keypoints       = (const float*)d_in[4];
    const float* keypoint_logits    = (const float*)d_in[5];
    const int*   labels             = (const int*)d_in[6];
    const int*   kmi                = (const int*)d_in[7];

    roiheads_fused<<<GRID, 256, 0, stream>>>(
        class_logits, box_regression, regression_targets, proposals,
        gt_keypoints, keypoint_logits, labels, kmi,
        (float*)d_ws, (float*)d_out);
}